// Round 10
// baseline (475.356 us; speedup 1.0000x reference)
//
#include <hip/hip_runtime.h>
#include <stdint.h>

// EdgeConv fused: out[i] = max over edges (j->i) of MLP3(concat[x_i, x_j-x_i])
// Layer-1 split: e@W1 = x_i@(W1a-W1b) + x_j@W1b. Per-node ac[n] = [a|c] (fp16, MFMA-computed).
// Counting-sort edges by dst; k_edge: 128 edges/block, 512 threads (8 waves x 32ch),
// halves per-block weight L2 streaming (was 1/3 of chip L2 BW at EPB=64 — R9 analysis).
// Register regime identical to R9: acc 64 AGPR + ~64 arch = 4 waves/SIMD, no spill.

#define N_NODES 50000
#define N_EDGES 800000
#define EPB 128
#define NBLK 6250              // 800000/128 exactly

typedef __attribute__((ext_vector_type(4))) float f32x4;
typedef __attribute__((ext_vector_type(8))) _Float16 f16x8;
typedef __attribute__((ext_vector_type(4))) unsigned int u32x4;
typedef __attribute__((ext_vector_type(2))) unsigned int u32x2;

__device__ __forceinline__ unsigned int pkrtz(float a, float b){   // f32x2 -> packed fp16
  auto p = __builtin_amdgcn_cvt_pkrtz(a, b);
  return __builtin_bit_cast(unsigned int, p);
}
__device__ __forceinline__ unsigned int f16bits(float f){
  _Float16 h = (_Float16)f;
  return (unsigned int)__builtin_bit_cast(unsigned short, h);
}
// packed fp16: relu(a + b), 2 channels per instruction
__device__ __forceinline__ unsigned int pkadd_relu(unsigned int a, unsigned int b){
  unsigned int s, r;
  asm("v_pk_add_f16 %0, %1, %2" : "=v"(s) : "v"(a), "v"(b));
  asm("v_pk_max_f16 %0, %1, %2" : "=v"(r) : "v"(s), "v"(0u));
  return r;
}
// monotone float->uint map: f1<f2 <=> map(f1)<map(f2)
__device__ __forceinline__ unsigned int fmap(float f){
  unsigned int u = __builtin_bit_cast(unsigned int, f);
  return (u & 0x80000000u) ? ~u : (u | 0x80000000u);
}
// int64 vs int32 edge_index: odd u32 slots of first 8 entries all zero <=> int64
__device__ __forceinline__ bool is64(const unsigned int* e){
  return (e[1] | e[3] | e[5] | e[7] | e[9] | e[11] | e[13] | e[15]) == 0u;
}

// ---- counting sort by dst: histogram ----
extern "C" __global__ void k_hist(const void* __restrict__ eidx, unsigned int* __restrict__ cnt){
  int i = blockIdx.x * 256 + threadIdx.x;
  int d = is64((const unsigned int*)eidx)
        ? (int)((const long long*)eidx)[N_EDGES + i]
        : ((const int*)eidx)[N_EDGES + i];
  atomicAdd(&cnt[d], 1u);
}

// ---- parallel exclusive scan over 50000 counters ----
extern "C" __global__ void k_psum(const unsigned int* __restrict__ cnt, unsigned int* __restrict__ bsum){
  __shared__ unsigned int red[4];
  const int b = blockIdx.x, t = threadIdx.x, i = b * 256 + t;
  unsigned int v = (i < N_NODES) ? cnt[i] : 0u;
  #pragma unroll
  for (int d = 32; d; d >>= 1) v += __shfl_down(v, d, 64);
  if ((t & 63) == 0) red[t >> 6] = v;
  __syncthreads();
  if (t == 0) bsum[b] = red[0] + red[1] + red[2] + red[3];
}
extern "C" __global__ void __launch_bounds__(256) k_bscan(const unsigned int* __restrict__ bsum,
                                                          unsigned int* __restrict__ bbase){
  __shared__ unsigned int s[256];
  const int t = threadIdx.x;
  unsigned int v = (t < 196) ? bsum[t] : 0u;
  s[t] = v; __syncthreads();
  for (int d = 1; d < 256; d <<= 1){
    unsigned int u = (t >= d) ? s[t - d] : 0u;
    __syncthreads(); s[t] += u; __syncthreads();
  }
  if (t < 196) bbase[t] = s[t] - v;               // exclusive
}
extern "C" __global__ void k_apply(const unsigned int* __restrict__ cnt,
                                   const unsigned int* __restrict__ bbase,
                                   unsigned int* __restrict__ off){
  __shared__ unsigned int s[256];
  const int b = blockIdx.x, t = threadIdx.x, i = b * 256 + t;
  unsigned int v = (i < N_NODES) ? cnt[i] : 0u;
  s[t] = v; __syncthreads();
  for (int d = 1; d < 256; d <<= 1){
    unsigned int u = (t >= d) ? s[t - d] : 0u;
    __syncthreads(); s[t] += u; __syncthreads();
  }
  if (i < N_NODES) off[i] = bbase[b] + s[t] - v;  // exclusive prefix
}

// ---- scatter edges into dst-sorted order, packed (src | dst<<16) ----
extern "C" __global__ void k_bucket(const void* __restrict__ eidx,
                                    unsigned int* __restrict__ cur, unsigned int* __restrict__ sPair){
  int i = blockIdx.x * 256 + threadIdx.x;
  int s, d;
  if (is64((const unsigned int*)eidx)){
    const long long* p = (const long long*)eidx;
    s = (int)p[i]; d = (int)p[N_EDGES + i];
  } else {
    const int* p = (const int*)eidx;
    s = p[i]; d = p[N_EDGES + i];
  }
  unsigned int pos = atomicAdd(&cur[d], 1u);
  sPair[pos] = (unsigned int)s | ((unsigned int)d << 16);    // both < 50000 < 2^16
}

// ---- weight prep: W2^T, W3^T (256x256) and Wd (512x128) into fp16 MFMA A-frag order ----
extern "C" __global__ void k_wprep(const float* __restrict__ W1, const float* __restrict__ W2,
                                   const float* __restrict__ W3,
                                   unsigned short* __restrict__ w2s, unsigned short* __restrict__ w3s,
                                   unsigned short* __restrict__ wdf){
  int t = blockIdx.x * 256 + threadIdx.x;              // 0..24575
  if (t < 16384){                                      // W2 / W3: K=256, 8 ks-blocks
    const float* W = (t & 8192) ? W3 : W2;
    unsigned short* o = (t & 8192) ? w3s : w2s;
    int r = t & 8191, lane = r & 63, blk = r >> 6;
    int m  = (blk >> 3) * 16 + (lane & 15);
    int k0 = (blk & 7) * 32 + (lane >> 4) * 8;
    u32x4 ov;
    #pragma unroll
    for (int j = 0; j < 4; j++){
      unsigned int lo = f16bits(W[(size_t)(k0 + 2*j    ) * 256 + m]);   // A[m][k] = W[k][m]
      unsigned int hi = f16bits(W[(size_t)(k0 + 2*j + 1) * 256 + m]);
      ov[j] = lo | (hi << 16);
    }
    *(u32x4*)(o + (size_t)r * 8) = ov;
  } else {                                             // Wd: 512 rows, K=128, 4 ks-blocks
    int r = t - 16384, lane = r & 63, blk = r >> 6;    // blk 0..127
    int m  = (blk >> 2) * 16 + (lane & 15);            // 0..511
    int k0 = (blk & 3) * 32 + (lane >> 4) * 8;         // 0..127
    u32x4 ov;
    #pragma unroll
    for (int j = 0; j < 4; j++){
      float vlo, vhi;
      int ka = k0 + 2*j, kb = k0 + 2*j + 1;
      if (m < 256){
        vlo = W1[(size_t)ka * 256 + m] - W1[(size_t)(ka + 128) * 256 + m];
        vhi = W1[(size_t)kb * 256 + m] - W1[(size_t)(kb + 128) * 256 + m];
      } else {
        vlo = W1[(size_t)(ka + 128) * 256 + (m - 256)];
        vhi = W1[(size_t)(kb + 128) * 256 + (m - 256)];
      }
      ov[j] = f16bits(vlo) | (f16bits(vhi) << 16);
    }
    *(u32x4*)(wdf + (size_t)r * 8) = ov;
  }
}

// ---- per-node precompute via MFMA: ac[n] = [a|c] fp16 ----
extern "C" __global__ void __launch_bounds__(256) k_acm(
    const float* __restrict__ x, const unsigned short* __restrict__ wdf,
    const float* __restrict__ b1, unsigned short* __restrict__ acb){
  __shared__ unsigned char smx[16384];                 // 64 nodes x 128 ch fp16
  const int tid = threadIdx.x, lane = tid & 63, w = tid >> 6;
  const int n0 = blockIdx.x * 64;
  {
    const int nl = tid >> 2, q = tid & 3;
    int node = n0 + nl; if (node > N_NODES - 1) node = N_NODES - 1;
    const f32x4* xp = (const f32x4*)(x + (size_t)node * 128 + q * 32);
    unsigned char* base = smx + (((nl >> 4) * 256 + q * 64 + (nl & 15)) << 4);
    #pragma unroll
    for (int s = 0; s < 4; s++){
      f32x4 v0 = xp[s * 2], v1 = xp[s * 2 + 1];
      u32x4 ov = { pkrtz(v0[0], v0[1]), pkrtz(v0[2], v0[3]),
                   pkrtz(v1[0], v1[1]), pkrtz(v1[2], v1[3]) };
      *(u32x4*)(base + s * 256) = ov;
    }
  }
  __syncthreads();
  const int lm = lane & 15, g = lane >> 4;
  f32x4 acc[8][4];
  #pragma unroll
  for (int mf = 0; mf < 8; mf++)
    #pragma unroll
    for (int nf = 0; nf < 4; nf++) acc[mf][nf] = (f32x4){0.f, 0.f, 0.f, 0.f};
  #pragma unroll
  for (int ks = 0; ks < 4; ks++){
    f16x8 af[8], bfr[4];
    #pragma unroll
    for (int mf = 0; mf < 8; mf++)
      af[mf] = __builtin_bit_cast(f16x8, *(const u32x4*)(wdf + (size_t)(((w * 8 + mf) * 4 + ks) * 64 + lane) * 8));
    #pragma unroll
    for (int nf = 0; nf < 4; nf++)
      bfr[nf] = __builtin_bit_cast(f16x8, *(const u32x4*)(smx + nf * 4096 + ks * 1024 + lane * 16));
    #pragma unroll
    for (int mf = 0; mf < 8; mf++)
      #pragma unroll
      for (int nf = 0; nf < 4; nf++)
        acc[mf][nf] = __builtin_amdgcn_mfma_f32_16x16x32_f16(af[mf], bfr[nf], acc[mf][nf], 0, 0, 0);
  }
  #pragma unroll
  for (int mf = 0; mf < 8; mf++){
    const int m0 = w * 128 + mf * 16 + g * 4;          // w<2 -> a half (bias), w>=2 -> c half
    f32x4 bb = (f32x4){0.f, 0.f, 0.f, 0.f};
    if (w < 2) bb = *(const f32x4*)(b1 + m0);
    #pragma unroll
    for (int nf = 0; nf < 4; nf++){
      int node = n0 + nf * 16 + lm;
      if (node < N_NODES){
        u32x2 pv = { pkrtz(acc[mf][nf][0] + bb[0], acc[mf][nf][1] + bb[1]),
                     pkrtz(acc[mf][nf][2] + bb[2], acc[mf][nf][3] + bb[3]) };
        *(u32x2*)(acb + (size_t)node * 512 + m0) = pv;
      }
    }
  }
}

// ---- fused edge MLP on dst-sorted edges: 128 edges/block, 8 waves (32 ch each) ----
// h1/h2 fragment-linear LDS (64KB): ch c of edge e at 16B-slot
//   (e>>4)*512 + (c>>5)*64 + ((c>>3)&3)*16 + (e&15); B-frag read conflict-free b128.
// Bias via MFMA C-in init. h3 staged f32 in two 64-row rounds (reuses 64KB);
// scan parallelized: thread pair (ch, sub) handles even/odd rows (dst-sorted => monotone).
extern "C" __global__ void __launch_bounds__(512, 4) k_edge(
    const unsigned short* __restrict__ acb,
    const unsigned short* __restrict__ w2f, const unsigned short* __restrict__ w3f,
    const float* __restrict__ b2, const float* __restrict__ b3,
    const unsigned int* __restrict__ sPair,
    unsigned int* __restrict__ outu){
  __shared__ unsigned char sm[65536];                  // 128 edges x 256 ch fp16 / 64-row f32 stage
  __shared__ int dstI[EPB];
  __shared__ int srcI[EPB];
  const int tid = threadIdx.x;
  const int lane = tid & 63;
  const int w = tid >> 6;                              // 0..7

  // bijective XCD chunk swizzle: 6250 = 8*781 + 2
  const int bid = blockIdx.x;
  const int xcd = bid & 7, idx = bid >> 3;
  const int sb = (xcd < 2) ? xcd * 782 : 2 * 782 + (xcd - 2) * 781;
  const int e0 = (sb + idx) * EPB;

  // prefetch W2 ks=0 A-frags (wave w owns mf-groups 2w, 2w+1)
  f16x8 afp[2];
  #pragma unroll
  for (int mf = 0; mf < 2; mf++)
    afp[mf] = __builtin_bit_cast(f16x8, *(const u32x4*)(w2f + (size_t)(((w * 2 + mf) * 8 + 0) * 64 + lane) * 8));

  if (tid < EPB){
    unsigned int pr = sPair[e0 + tid];
    srcI[tid] = (int)(pr & 0xFFFFu);
    dstI[tid] = (int)(pr >> 16);
  }
  __syncthreads();

  { // gather: h1 = relu(a[dst]+c[src]) packed fp16. 4 threads/edge, 64 ch each.
    const int e = tid >> 2, q = tid & 3;
    const unsigned short* pa = acb + (size_t)dstI[e] * 512 + q * 64;         // a half (cache-hot)
    const unsigned short* pc = acb + (size_t)srcI[e] * 512 + 256 + q * 64;   // c half
    unsigned char* base = sm + (e >> 4) * 8192 + (e & 15) * 16;
    #pragma unroll
    for (int j = 0; j < 8; j++){                        // chunk j: channels q*64+j*8 ..+7
      u32x4 ua = *(const u32x4*)(pa + j * 8);
      u32x4 uc = *(const u32x4*)(pc + j * 8);
      u32x4 ov;
      #pragma unroll
      for (int t2 = 0; t2 < 4; t2++) ov[t2] = pkadd_relu(ua[t2], uc[t2]);
      *(u32x4*)(base + (q * 2 + (j >> 2)) * 1024 + (j & 3) * 256) = ov;
    }
  }
  __syncthreads();

  const int lm = lane & 15, g = lane >> 4;
  f32x4 acc[2][8];
  { // init acc with b2 (C-in bias): lane rows = channels m0..m0+3
    #pragma unroll
    for (int mf = 0; mf < 2; mf++){
      const f32x4 bb = *(const f32x4*)(b2 + w * 32 + mf * 16 + g * 4);
      #pragma unroll
      for (int nf = 0; nf < 8; nf++) acc[mf][nf] = bb;
    }
  }

  // G1: h2^T = W2^T @ h1^T + b2
  #pragma unroll
  for (int ks = 0; ks < 8; ks++){
    f16x8 af[2], bfr[8];
    #pragma unroll
    for (int mf = 0; mf < 2; mf++)
      af[mf] = (ks == 0) ? afp[mf]
             : __builtin_bit_cast(f16x8, *(const u32x4*)(w2f + (size_t)(((w * 2 + mf) * 8 + ks) * 64 + lane) * 8));
    #pragma unroll
    for (int nf = 0; nf < 8; nf++)
      bfr[nf] = __builtin_bit_cast(f16x8, *(const u32x4*)(sm + nf * 8192 + ks * 1024 + lane * 16));
    __builtin_amdgcn_s_setprio(1);
    #pragma unroll
    for (int mf = 0; mf < 2; mf++)
      #pragma unroll
      for (int nf = 0; nf < 8; nf++)
        acc[mf][nf] = __builtin_amdgcn_mfma_f32_16x16x32_f16(af[mf], bfr[nf], acc[mf][nf], 0, 0, 0);
    __builtin_amdgcn_s_setprio(0);
  }

  // prefetch W3 ks=0 before the barrier
  #pragma unroll
  for (int mf = 0; mf < 2; mf++)
    afp[mf] = __builtin_bit_cast(f16x8, *(const u32x4*)(w3f + (size_t)(((w * 2 + mf) * 8 + 0) * 64 + lane) * 8));
  __syncthreads();   // all waves done reading h1

  { // relu -> h2 fp16, fragment-linear, in place (bias already in acc)
    #pragma unroll
    for (int mf = 0; mf < 2; mf++){
      const int m0 = w * 32 + mf * 16 + g * 4;
      const int boff = (m0 >> 5) * 1024 + ((m0 >> 3) & 3) * 256 + lm * 16 + (m0 & 7) * 2;
      #pragma unroll
      for (int nf = 0; nf < 8; nf++){
        float v0 = fmaxf(acc[mf][nf][0], 0.f);
        float v1 = fmaxf(acc[mf][nf][1], 0.f);
        float v2 = fmaxf(acc[mf][nf][2], 0.f);
        float v3 = fmaxf(acc[mf][nf][3], 0.f);
        u32x2 pv = { pkrtz(v0, v1), pkrtz(v2, v3) };
        *(u32x2*)(sm + nf * 8192 + boff) = pv;
      }
    }
  }
  __syncthreads();

  { // init acc with b3 for G2
    #pragma unroll
    for (int mf = 0; mf < 2; mf++){
      const f32x4 bb = *(const f32x4*)(b3 + w * 32 + mf * 16 + g * 4);
      #pragma unroll
      for (int nf = 0; nf < 8; nf++) acc[mf][nf] = bb;
    }
  }
  // G2: h3^T = W3^T @ h2^T + b3
  #pragma unroll
  for (int ks = 0; ks < 8; ks++){
    f16x8 af[2], bfr[8];
    #pragma unroll
    for (int mf = 0; mf < 2; mf++)
      af[mf] = (ks == 0) ? afp[mf]
             : __builtin_bit_cast(f16x8, *(const u32x4*)(w3f + (size_t)(((w * 2 + mf) * 8 + ks) * 64 + lane) * 8));
    #pragma unroll
    for (int nf = 0; nf < 8; nf++)
      bfr[nf] = __builtin_bit_cast(f16x8, *(const u32x4*)(sm + nf * 8192 + ks * 1024 + lane * 16));
    __builtin_amdgcn_s_setprio(1);
    #pragma unroll
    for (int mf = 0; mf < 2; mf++)
      #pragma unroll
      for (int nf = 0; nf < 8; nf++)
        acc[mf][nf] = __builtin_amdgcn_mfma_f32_16x16x32_f16(af[mf], bfr[nf], acc[mf][nf], 0, 0, 0);
    __builtin_amdgcn_s_setprio(0);
  }
  __syncthreads();   // all h2 reads done before h3 staging overwrites the buffer

  // h3 staging (f32, 64 rows per round, XOR) + per-dst-group float running max.
  // Thread pair: ch = tid&255, sub = tid>>8 handles even/odd rows; dsts monotone per sub.
  float vmaxf = -__builtin_inff();
  int curDst = dstI[0];
  const int ch = tid & 255, sub = tid >> 8;
  #pragma unroll
  for (int round = 0; round < 2; round++){
    #pragma unroll
    for (int mf = 0; mf < 2; mf++){
      const int m0 = w * 32 + mf * 16 + g * 4;
      #pragma unroll
      for (int nfl = 0; nfl < 4; nfl++){
        const int rl = nfl * 16 + lm;                   // row within round (0..63)
        const int nf = round * 4 + nfl;
        *(f32x4*)(sm + rl * 1024 + ((m0 * 4) ^ ((rl & 7) << 4))) = acc[mf][nf];
      }
    }
    __syncthreads();
    for (int k = 0; k < 32; k++){
      const int rl = 2 * k + sub;
      float v = *(const float*)(sm + rl * 1024 + ((ch * 4) ^ ((rl & 7) << 4)));
      const int d = dstI[round * 64 + rl];
      if (d != curDst){                                 // flush previous group (coalesced 1KB)
        atomicMax(outu + (size_t)curDst * 256 + ch, fmap(vmaxf));
        curDst = d; vmaxf = -__builtin_inff();
      }
      vmaxf = fmaxf(vmaxf, v);
    }
    __syncthreads();                                    // scan reads done before next staging
  }
  atomicMax(outu + (size_t)curDst * 256 + ch, fmap(vmaxf));   // final flush
}

// ---- unmap uint->float; untouched (0) cells = empty segments -> 0.0 ----
extern "C" __global__ void k_fix(u32x4* __restrict__ o){
  size_t i = (size_t)blockIdx.x * 256 + threadIdx.x;
  u32x4 u = o[i];
  #pragma unroll
  for (int j = 0; j < 4; j++)
    u[j] = (u[j] == 0u) ? 0u : ((u[j] & 0x80000000u) ? (u[j] ^ 0x80000000u) : ~u[j]);
  o[i] = u;
}

extern "C" void kernel_launch(void* const* d_in, const int* in_sizes, int n_in,
                              void* d_out, int out_size, void* d_ws, size_t ws_size,
                              hipStream_t stream){
  const float* x  = (const float*)d_in[0];
  const void*  ei = d_in[1];
  const float* W1 = (const float*)d_in[2];
  const float* b1 = (const float*)d_in[3];
  const float* W2 = (const float*)d_in[4];
  const float* b2 = (const float*)d_in[5];
  const float* W3 = (const float*)d_in[6];
  const float* b3 = (const float*)d_in[7];

  const size_t AC_BYTES = (size_t)N_NODES * 512 * 2;  // 51.2 MB combined [a|c] fp16
  const size_t W_BYTES  = 256 * 256 * 2;              // 128 KB each: w2s, w3s, wdf
  const size_t P_BYTES  = (size_t)N_EDGES * 4;        // 3.2 MB sorted pairs
  const size_t C_BYTES  = 200704;                     // 50000 u32, padded
  char* ws = (char*)d_ws;
  size_t o = 0;
  unsigned short* acb  = (unsigned short*)(ws + o); o += AC_BYTES;
  unsigned short* w2s  = (unsigned short*)(ws + o); o += W_BYTES;
  unsigned short* w3s  = (unsigned short*)(ws + o); o += W_BYTES;
  unsigned short* wdf  = (unsigned short*)(ws + o); o += W_BYTES;
  unsigned int*  sPair = (unsigned int*)(ws + o);   o += P_BYTES;
  unsigned int*  cnt   = (unsigned int*)(ws + o);   o += C_BYTES;
  unsigned int*  offA  = (unsigned int*)(ws + o);   o += C_BYTES;
  unsigned int*  bsum  = (unsigned int*)(ws + o);   o += 1024;
  unsigned int*  bbase = (unsigned int*)(ws + o);   o += 1024;
  if (ws_size < o) return;   // insufficient scratch

  (void)hipMemsetAsync(cnt, 0, C_BYTES, stream);
  k_hist<<<N_EDGES / 256, 256, 0, stream>>>(ei, cnt);
  k_psum<<<196, 256, 0, stream>>>(cnt, bsum);
  k_bscan<<<1, 256, 0, stream>>>(bsum, bbase);
  k_apply<<<196, 256, 0, stream>>>(cnt, bbase, offA);
  k_bucket<<<N_EDGES / 256, 256, 0, stream>>>(ei, offA, sPair);
  k_wprep<<<96, 256, 0, stream>>>(W1, W2, W3, w2s, w3s, wdf);
  k_acm<<<(N_NODES + 63) / 64, 256, 0, stream>>>(x, wdf, b1, acb);
  (void)hipMemsetAsync(d_out, 0, (size_t)out_size * 4, stream);
  k_edge<<<NBLK, 512, 0, stream>>>(acb, w2s, w3s, b2, b3, sPair, (unsigned int*)d_out);
  k_fix<<<out_size / 1024, 256, 0, stream>>>((u32x4*)d_out);
}

// Round 11
// 450.041 us; speedup vs baseline: 1.0563x; 1.0563x over previous
//
#include <hip/hip_runtime.h>
#include <stdint.h>

// EdgeConv fused: out[i] = max over edges (j->i) of MLP3(concat[x_i, x_j-x_i])
// Layer-1 split: e@W1 = x_i@(W1a-W1b) + x_j@W1b. Per-node ac[n] = [a|c] (fp16, MFMA-computed).
// Counting-sort edges by dst; k_edge: 64 edges/block @ 4 blocks/CU (R10 lesson: EPB=128
// regressed — 8-wave barriers + 2 blocks/CU lose more than the weight-stream halving gains).
// R11: h3 staged as packed fp16 in ONE 32KB round (2 barriers removed); scan uses
// v_pk_max_f16 over channel pairs, 32 iters (was 64 f32 iters over 2 rounds).

#define N_NODES 50000
#define N_EDGES 800000
#define EPB 64
#define NBLK 12500             // 800000/64 exactly

typedef __attribute__((ext_vector_type(4))) float f32x4;
typedef __attribute__((ext_vector_type(8))) _Float16 f16x8;
typedef __attribute__((ext_vector_type(4))) unsigned int u32x4;
typedef __attribute__((ext_vector_type(2))) unsigned int u32x2;

__device__ __forceinline__ unsigned int pkrtz(float a, float b){   // f32x2 -> packed fp16 (RTZ)
  auto p = __builtin_amdgcn_cvt_pkrtz(a, b);
  return __builtin_bit_cast(unsigned int, p);
}
__device__ __forceinline__ unsigned int f16bits(float f){
  _Float16 h = (_Float16)f;
  return (unsigned int)__builtin_bit_cast(unsigned short, h);
}
// packed fp16: relu(a + b), 2 channels per instruction
__device__ __forceinline__ unsigned int pkadd_relu(unsigned int a, unsigned int b){
  unsigned int s, r;
  asm("v_pk_add_f16 %0, %1, %2" : "=v"(s) : "v"(a), "v"(b));
  asm("v_pk_max_f16 %0, %1, %2" : "=v"(r) : "v"(s), "v"(0u));
  return r;
}
__device__ __forceinline__ unsigned int pkmax(unsigned int a, unsigned int b){
  unsigned int r;
  asm("v_pk_max_f16 %0, %1, %2" : "=v"(r) : "v"(a), "v"(b));
  return r;
}
__device__ __forceinline__ float f16lo2f(unsigned int v){
  return (float)__builtin_bit_cast(_Float16, (unsigned short)(v & 0xFFFFu));
}
__device__ __forceinline__ float f16hi2f(unsigned int v){
  return (float)__builtin_bit_cast(_Float16, (unsigned short)(v >> 16));
}
// monotone float->uint map: f1<f2 <=> map(f1)<map(f2); finite values map nonzero
__device__ __forceinline__ unsigned int fmap(float f){
  unsigned int u = __builtin_bit_cast(unsigned int, f);
  return (u & 0x80000000u) ? ~u : (u | 0x80000000u);
}
// int64 vs int32 edge_index: odd u32 slots of first 8 entries all zero <=> int64
__device__ __forceinline__ bool is64(const unsigned int* e){
  return (e[1] | e[3] | e[5] | e[7] | e[9] | e[11] | e[13] | e[15]) == 0u;
}

// ---- counting sort by dst: histogram ----
extern "C" __global__ void k_hist(const void* __restrict__ eidx, unsigned int* __restrict__ cnt){
  int i = blockIdx.x * 256 + threadIdx.x;
  int d = is64((const unsigned int*)eidx)
        ? (int)((const long long*)eidx)[N_EDGES + i]
        : ((const int*)eidx)[N_EDGES + i];
  atomicAdd(&cnt[d], 1u);
}

// ---- parallel exclusive scan over 50000 counters ----
extern "C" __global__ void k_psum(const unsigned int* __restrict__ cnt, unsigned int* __restrict__ bsum){
  __shared__ unsigned int red[4];
  const int b = blockIdx.x, t = threadIdx.x, i = b * 256 + t;
  unsigned int v = (i < N_NODES) ? cnt[i] : 0u;
  #pragma unroll
  for (int d = 32; d; d >>= 1) v += __shfl_down(v, d, 64);
  if ((t & 63) == 0) red[t >> 6] = v;
  __syncthreads();
  if (t == 0) bsum[b] = red[0] + red[1] + red[2] + red[3];
}
extern "C" __global__ void __launch_bounds__(256) k_bscan(const unsigned int* __restrict__ bsum,
                                                          unsigned int* __restrict__ bbase){
  __shared__ unsigned int s[256];
  const int t = threadIdx.x;
  unsigned int v = (t < 196) ? bsum[t] : 0u;
  s[t] = v; __syncthreads();
  for (int d = 1; d < 256; d <<= 1){
    unsigned int u = (t >= d) ? s[t - d] : 0u;
    __syncthreads(); s[t] += u; __syncthreads();
  }
  if (t < 196) bbase[t] = s[t] - v;               // exclusive
}
extern "C" __global__ void k_apply(const unsigned int* __restrict__ cnt,
                                   const unsigned int* __restrict__ bbase,
                                   unsigned int* __restrict__ off){
  __shared__ unsigned int s[256];
  const int b = blockIdx.x, t = threadIdx.x, i = b * 256 + t;
  unsigned int v = (i < N_NODES) ? cnt[i] : 0u;
  s[t] = v; __syncthreads();
  for (int d = 1; d < 256; d <<= 1){
    unsigned int u = (t >= d) ? s[t - d] : 0u;
    __syncthreads(); s[t] += u; __syncthreads();
  }
  if (i < N_NODES) off[i] = bbase[b] + s[t] - v;  // exclusive prefix
}

// ---- scatter edges into dst-sorted order, packed (src | dst<<16) ----
extern "C" __global__ void k_bucket(const void* __restrict__ eidx,
                                    unsigned int* __restrict__ cur, unsigned int* __restrict__ sPair){
  int i = blockIdx.x * 256 + threadIdx.x;
  int s, d;
  if (is64((const unsigned int*)eidx)){
    const long long* p = (const long long*)eidx;
    s = (int)p[i]; d = (int)p[N_EDGES + i];
  } else {
    const int* p = (const int*)eidx;
    s = p[i]; d = p[N_EDGES + i];
  }
  unsigned int pos = atomicAdd(&cur[d], 1u);
  sPair[pos] = (unsigned int)s | ((unsigned int)d << 16);    // both < 50000 < 2^16
}

// ---- weight prep: W2^T, W3^T (256x256) and Wd (512x128) into fp16 MFMA A-frag order ----
extern "C" __global__ void k_wprep(const float* __restrict__ W1, const float* __restrict__ W2,
                                   const float* __restrict__ W3,
                                   unsigned short* __restrict__ w2s, unsigned short* __restrict__ w3s,
                                   unsigned short* __restrict__ wdf){
  int t = blockIdx.x * 256 + threadIdx.x;              // 0..24575
  if (t < 16384){                                      // W2 / W3: K=256, 8 ks-blocks
    const float* W = (t & 8192) ? W3 : W2;
    unsigned short* o = (t & 8192) ? w3s : w2s;
    int r = t & 8191, lane = r & 63, blk = r >> 6;
    int m  = (blk >> 3) * 16 + (lane & 15);
    int k0 = (blk & 7) * 32 + (lane >> 4) * 8;
    u32x4 ov;
    #pragma unroll
    for (int j = 0; j < 4; j++){
      unsigned int lo = f16bits(W[(size_t)(k0 + 2*j    ) * 256 + m]);   // A[m][k] = W[k][m]
      unsigned int hi = f16bits(W[(size_t)(k0 + 2*j + 1) * 256 + m]);
      ov[j] = lo | (hi << 16);
    }
    *(u32x4*)(o + (size_t)r * 8) = ov;
  } else {                                             // Wd: 512 rows, K=128, 4 ks-blocks
    int r = t - 16384, lane = r & 63, blk = r >> 6;    // blk 0..127
    int m  = (blk >> 2) * 16 + (lane & 15);            // 0..511
    int k0 = (blk & 3) * 32 + (lane >> 4) * 8;         // 0..127
    u32x4 ov;
    #pragma unroll
    for (int j = 0; j < 4; j++){
      float vlo, vhi;
      int ka = k0 + 2*j, kb = k0 + 2*j + 1;
      if (m < 256){
        vlo = W1[(size_t)ka * 256 + m] - W1[(size_t)(ka + 128) * 256 + m];
        vhi = W1[(size_t)kb * 256 + m] - W1[(size_t)(kb + 128) * 256 + m];
      } else {
        vlo = W1[(size_t)(ka + 128) * 256 + (m - 256)];
        vhi = W1[(size_t)(kb + 128) * 256 + (m - 256)];
      }
      ov[j] = f16bits(vlo) | (f16bits(vhi) << 16);
    }
    *(u32x4*)(wdf + (size_t)r * 8) = ov;
  }
}

// ---- per-node precompute via MFMA: ac[n] = [a|c] fp16 ----
extern "C" __global__ void __launch_bounds__(256) k_acm(
    const float* __restrict__ x, const unsigned short* __restrict__ wdf,
    const float* __restrict__ b1, unsigned short* __restrict__ acb){
  __shared__ unsigned char smx[16384];                 // 64 nodes x 128 ch fp16
  const int tid = threadIdx.x, lane = tid & 63, w = tid >> 6;
  const int n0 = blockIdx.x * 64;
  {
    const int nl = tid >> 2, q = tid & 3;
    int node = n0 + nl; if (node > N_NODES - 1) node = N_NODES - 1;
    const f32x4* xp = (const f32x4*)(x + (size_t)node * 128 + q * 32);
    unsigned char* base = smx + (((nl >> 4) * 256 + q * 64 + (nl & 15)) << 4);
    #pragma unroll
    for (int s = 0; s < 4; s++){
      f32x4 v0 = xp[s * 2], v1 = xp[s * 2 + 1];
      u32x4 ov = { pkrtz(v0[0], v0[1]), pkrtz(v0[2], v0[3]),
                   pkrtz(v1[0], v1[1]), pkrtz(v1[2], v1[3]) };
      *(u32x4*)(base + s * 256) = ov;
    }
  }
  __syncthreads();
  const int lm = lane & 15, g = lane >> 4;
  f32x4 acc[8][4];
  #pragma unroll
  for (int mf = 0; mf < 8; mf++)
    #pragma unroll
    for (int nf = 0; nf < 4; nf++) acc[mf][nf] = (f32x4){0.f, 0.f, 0.f, 0.f};
  #pragma unroll
  for (int ks = 0; ks < 4; ks++){
    f16x8 af[8], bfr[4];
    #pragma unroll
    for (int mf = 0; mf < 8; mf++)
      af[mf] = __builtin_bit_cast(f16x8, *(const u32x4*)(wdf + (size_t)(((w * 8 + mf) * 4 + ks) * 64 + lane) * 8));
    #pragma unroll
    for (int nf = 0; nf < 4; nf++)
      bfr[nf] = __builtin_bit_cast(f16x8, *(const u32x4*)(smx + nf * 4096 + ks * 1024 + lane * 16));
    #pragma unroll
    for (int mf = 0; mf < 8; mf++)
      #pragma unroll
      for (int nf = 0; nf < 4; nf++)
        acc[mf][nf] = __builtin_amdgcn_mfma_f32_16x16x32_f16(af[mf], bfr[nf], acc[mf][nf], 0, 0, 0);
  }
  #pragma unroll
  for (int mf = 0; mf < 8; mf++){
    const int m0 = w * 128 + mf * 16 + g * 4;          // w<2 -> a half (bias), w>=2 -> c half
    f32x4 bb = (f32x4){0.f, 0.f, 0.f, 0.f};
    if (w < 2) bb = *(const f32x4*)(b1 + m0);
    #pragma unroll
    for (int nf = 0; nf < 4; nf++){
      int node = n0 + nf * 16 + lm;
      if (node < N_NODES){
        u32x2 pv = { pkrtz(acc[mf][nf][0] + bb[0], acc[mf][nf][1] + bb[1]),
                     pkrtz(acc[mf][nf][2] + bb[2], acc[mf][nf][3] + bb[3]) };
        *(u32x2*)(acb + (size_t)node * 512 + m0) = pv;
      }
    }
  }
}

// ---- fused edge MLP on dst-sorted edges: 64 edges/block, 4 waves, 4 blocks/CU ----
// h1/h2 fragment-linear LDS: ch c of edge e at 16B-slot (e>>4)*512 + (c>>5)*64 + ((c>>3)&3)*16 + (e&15).
// B-frag read = sm + nf*8192 + ks*1024 + lane*16 -> conflict-free ds_read_b128.
// Bias via MFMA C-in init. h3 staged packed-fp16 in ONE 32KB round; pk_max_f16 scan
// over channel pairs (p=tid&127, sub=tid>>7 rows even/odd; dst-sorted => monotone per sub).
extern "C" __global__ void __launch_bounds__(256, 4) k_edge(
    const unsigned short* __restrict__ acb,
    const unsigned short* __restrict__ w2f, const unsigned short* __restrict__ w3f,
    const float* __restrict__ b2, const float* __restrict__ b3,
    const unsigned int* __restrict__ sPair,
    unsigned int* __restrict__ outu){
  __shared__ unsigned char sm[32768];                  // 64 edges x 256 ch fp16
  __shared__ int dstI[EPB];
  __shared__ int srcI[EPB];
  const int tid = threadIdx.x;
  const int lane = tid & 63;
  const int w = tid >> 6;

  // bijective XCD chunk swizzle: 12500 = 8*1562 + 4
  const int bid = blockIdx.x;
  const int xcd = bid & 7, idx = bid >> 3;
  const int sb = (xcd < 4) ? xcd * 1563 : 4 * 1563 + (xcd - 4) * 1562;
  const int e0 = (sb + idx) * EPB;

  // prefetch W2 ks=0 A-frags
  f16x8 afp[4];
  #pragma unroll
  for (int mf = 0; mf < 4; mf++)
    afp[mf] = __builtin_bit_cast(f16x8, *(const u32x4*)(w2f + (size_t)(((w * 4 + mf) * 8 + 0) * 64 + lane) * 8));

  if (tid < EPB){
    unsigned int pr = sPair[e0 + tid];
    srcI[tid] = (int)(pr & 0xFFFFu);
    dstI[tid] = (int)(pr >> 16);
  }
  __syncthreads();

  { // gather: h1 = relu(a[dst]+c[src]) packed fp16. 4 threads/edge, 64 ch each.
    const int e = tid >> 2, q = tid & 3;
    const unsigned short* pa = acb + (size_t)dstI[e] * 512 + q * 64;         // a half (cache-hot)
    const unsigned short* pc = acb + (size_t)srcI[e] * 512 + 256 + q * 64;   // c half
    unsigned char* base = sm + (e >> 4) * 8192 + (e & 15) * 16;
    #pragma unroll
    for (int j = 0; j < 8; j++){                        // chunk j: channels q*64+j*8 ..+7
      u32x4 ua = *(const u32x4*)(pa + j * 8);
      u32x4 uc = *(const u32x4*)(pc + j * 8);
      u32x4 ov;
      #pragma unroll
      for (int t2 = 0; t2 < 4; t2++) ov[t2] = pkadd_relu(ua[t2], uc[t2]);
      *(u32x4*)(base + (q * 2 + (j >> 2)) * 1024 + (j & 3) * 256) = ov;
    }
  }
  __syncthreads();

  const int lm = lane & 15, g = lane >> 4;
  f32x4 acc[4][4];
  { // init acc with b2 (C-in bias): lane rows = channels m0..m0+3, same for all edges
    #pragma unroll
    for (int mf = 0; mf < 4; mf++){
      const f32x4 bb = *(const f32x4*)(b2 + w * 64 + mf * 16 + g * 4);
      #pragma unroll
      for (int nf = 0; nf < 4; nf++) acc[mf][nf] = bb;
    }
  }

  // G1: h2^T = W2^T @ h1^T + b2
  #pragma unroll
  for (int ks = 0; ks < 8; ks++){
    f16x8 af[4], bfr[4];
    #pragma unroll
    for (int mf = 0; mf < 4; mf++)
      af[mf] = (ks == 0) ? afp[mf]
             : __builtin_bit_cast(f16x8, *(const u32x4*)(w2f + (size_t)(((w * 4 + mf) * 8 + ks) * 64 + lane) * 8));
    #pragma unroll
    for (int nf = 0; nf < 4; nf++)
      bfr[nf] = __builtin_bit_cast(f16x8, *(const u32x4*)(sm + nf * 8192 + ks * 1024 + lane * 16));
    __builtin_amdgcn_s_setprio(1);
    #pragma unroll
    for (int mf = 0; mf < 4; mf++)
      #pragma unroll
      for (int nf = 0; nf < 4; nf++)
        acc[mf][nf] = __builtin_amdgcn_mfma_f32_16x16x32_f16(af[mf], bfr[nf], acc[mf][nf], 0, 0, 0);
    __builtin_amdgcn_s_setprio(0);
  }

  // prefetch W3 ks=0 before the barrier
  #pragma unroll
  for (int mf = 0; mf < 4; mf++)
    afp[mf] = __builtin_bit_cast(f16x8, *(const u32x4*)(w3f + (size_t)(((w * 4 + mf) * 8 + 0) * 64 + lane) * 8));
  __syncthreads();   // all waves done reading h1

  { // relu -> h2 fp16, fragment-linear, in place (bias already in acc)
    #pragma unroll
    for (int mf = 0; mf < 4; mf++){
      const int m0 = w * 64 + mf * 16 + g * 4;
      const int boff = (m0 >> 5) * 1024 + ((m0 >> 3) & 3) * 256 + lm * 16 + (m0 & 7) * 2;
      #pragma unroll
      for (int nf = 0; nf < 4; nf++){
        float v0 = fmaxf(acc[mf][nf][0], 0.f);
        float v1 = fmaxf(acc[mf][nf][1], 0.f);
        float v2 = fmaxf(acc[mf][nf][2], 0.f);
        float v3 = fmaxf(acc[mf][nf][3], 0.f);
        u32x2 pv = { pkrtz(v0, v1), pkrtz(v2, v3) };
        *(u32x2*)(sm + nf * 8192 + boff) = pv;
      }
    }
  }
  __syncthreads();

  { // init acc with b3 for G2
    #pragma unroll
    for (int mf = 0; mf < 4; mf++){
      const f32x4 bb = *(const f32x4*)(b3 + w * 64 + mf * 16 + g * 4);
      #pragma unroll
      for (int nf = 0; nf < 4; nf++) acc[mf][nf] = bb;
    }
  }
  // G2: h3^T = W3^T @ h2^T + b3
  #pragma unroll
  for (int ks = 0; ks < 8; ks++){
    f16x8 af[4], bfr[4];
    #pragma unroll
    for (int mf = 0; mf < 4; mf++)
      af[mf] = (ks == 0) ? afp[mf]
             : __builtin_bit_cast(f16x8, *(const u32x4*)(w3f + (size_t)(((w * 4 + mf) * 8 + ks) * 64 + lane) * 8));
    #pragma unroll
    for (int nf = 0; nf < 4; nf++)
      bfr[nf] = __builtin_bit_cast(f16x8, *(const u32x4*)(sm + nf * 8192 + ks * 1024 + lane * 16));
    __builtin_amdgcn_s_setprio(1);
    #pragma unroll
    for (int mf = 0; mf < 4; mf++)
      #pragma unroll
      for (int nf = 0; nf < 4; nf++)
        acc[mf][nf] = __builtin_amdgcn_mfma_f32_16x16x32_f16(af[mf], bfr[nf], acc[mf][nf], 0, 0, 0);
    __builtin_amdgcn_s_setprio(0);
  }
  __syncthreads();   // all h2 reads done before h3 staging overwrites the buffer

  { // h3 staging: packed fp16, 64 rows x 512B = 32KB, ONE round.
    // row r at sm + r*512; channel pair at byte (m0*2) ^ ((r&7)<<4) (8B-aligned stores)
    #pragma unroll
    for (int mf = 0; mf < 4; mf++){
      const int m0 = w * 64 + mf * 16 + g * 4;
      #pragma unroll
      for (int nf = 0; nf < 4; nf++){
        const int r = nf * 16 + lm;
        u32x2 pv = { pkrtz(acc[mf][nf][0], acc[mf][nf][1]),
                     pkrtz(acc[mf][nf][2], acc[mf][nf][3]) };
        *(u32x2*)(sm + r * 512 + ((m0 * 2) ^ ((r & 7) << 4))) = pv;
      }
    }
  }
  __syncthreads();

  // pk_max_f16 scan: thread (p = tid&127 -> channels 2p,2p+1; sub = tid>>7 -> rows 2k+sub).
  // dst-sorted => dst sequence monotone per sub; both subs flush via atomicMax (merges).
  {
    const int p = tid & 127, sub = tid >> 7;
    unsigned int vmax = 0xFC00FC00u;                    // packed (-inf, -inf)
    int curDst = dstI[sub];
    for (int k = 0; k < 32; k++){
      const int rl = 2 * k + sub;
      unsigned int v = *(const unsigned int*)(sm + rl * 512 + ((p * 4) ^ ((rl & 7) << 4)));
      const int d = dstI[rl];
      if (d != curDst){                                 // flush previous group
        unsigned int* o = outu + (size_t)curDst * 256 + 2 * p;
        atomicMax(o,     fmap(f16lo2f(vmax)));
        atomicMax(o + 1, fmap(f16hi2f(vmax)));
        curDst = d; vmax = 0xFC00FC00u;
      }
      vmax = pkmax(vmax, v);
    }
    unsigned int* o = outu + (size_t)curDst * 256 + 2 * p;
    atomicMax(o,     fmap(f16lo2f(vmax)));              // final flush
    atomicMax(o + 1, fmap(f16hi2f(vmax)));
  }
}

// ---- unmap uint->float; untouched (0) cells = empty segments -> 0.0 ----
extern "C" __global__ void k_fix(u32x4* __restrict__ o){
  size_t i = (size_t)blockIdx.x * 256 + threadIdx.x;
  u32x4 u = o[i];
  #pragma unroll
  for (int j = 0; j < 4; j++)
    u[j] = (u[j] == 0u) ? 0u : ((u[j] & 0x80000000u) ? (u[j] ^ 0x80000000u) : ~u[j]);
  o[i] = u;
}

extern "C" void kernel_launch(void* const* d_in, const int* in_sizes, int n_in,
                              void* d_out, int out_size, void* d_ws, size_t ws_size,
                              hipStream_t stream){
  const float* x  = (const float*)d_in[0];
  const void*  ei = d_in[1];
  const float* W1 = (const float*)d_in[2];
  const float* b1 = (const float*)d_in[3];
  const float* W2 = (const float*)d_in[4];
  const float* b2 = (const float*)d_in[5];
  const float* W3 = (const float*)d_in[6];
  const float* b3 = (const float*)d_in[7];

  const size_t AC_BYTES = (size_t)N_NODES * 512 * 2;  // 51.2 MB combined [a|c] fp16
  const size_t W_BYTES  = 256 * 256 * 2;              // 128 KB each: w2s, w3s, wdf
  const size_t P_BYTES  = (size_t)N_EDGES * 4;        // 3.2 MB sorted pairs
  const size_t C_BYTES  = 200704;                     // 50000 u32, padded
  char* ws = (char*)d_ws;
  size_t o = 0;
  unsigned short* acb  = (unsigned short*)(ws + o); o += AC_BYTES;
  unsigned short* w2s  = (unsigned short*)(ws + o); o += W_BYTES;
  unsigned short* w3s  = (unsigned short*)(ws + o); o += W_BYTES;
  unsigned short* wdf  = (unsigned short*)(ws + o); o += W_BYTES;
  unsigned int*  sPair = (unsigned int*)(ws + o);   o += P_BYTES;
  unsigned int*  cnt   = (unsigned int*)(ws + o);   o += C_BYTES;
  unsigned int*  offA  = (unsigned int*)(ws + o);   o += C_BYTES;
  unsigned int*  bsum  = (unsigned int*)(ws + o);   o += 1024;
  unsigned int*  bbase = (unsigned int*)(ws + o);   o += 1024;
  if (ws_size < o) return;   // insufficient scratch

  (void)hipMemsetAsync(cnt, 0, C_BYTES, stream);
  k_hist<<<N_EDGES / 256, 256, 0, stream>>>(ei, cnt);
  k_psum<<<196, 256, 0, stream>>>(cnt, bsum);
  k_bscan<<<1, 256, 0, stream>>>(bsum, bbase);
  k_apply<<<196, 256, 0, stream>>>(cnt, bbase, offA);
  k_bucket<<<N_EDGES / 256, 256, 0, stream>>>(ei, offA, sPair);
  k_wprep<<<96, 256, 0, stream>>>(W1, W2, W3, w2s, w3s, wdf);
  k_acm<<<(N_NODES + 63) / 64, 256, 0, stream>>>(x, wdf, b1, acb);
  (void)hipMemsetAsync(d_out, 0, (size_t)out_size * 4, stream);
  k_edge<<<NBLK, 256, 0, stream>>>(acb, w2s, w3s, b2, b3, sPair, (unsigned int*)d_out);
  k_fix<<<out_size / 1024, 256, 0, stream>>>((u32x4*)d_out);
}

// Round 12
// 432.297 us; speedup vs baseline: 1.0996x; 1.0410x over previous
//
#include <hip/hip_runtime.h>
#include <stdint.h>

// EdgeConv fused: out[i] = max over edges (j->i) of MLP3(concat[x_i, x_j-x_i])
// Layer-1 split: e@W1 = x_i@(W1a-W1b) + x_j@W1b. Per-node ac[n] = [a|c] (fp16, MFMA-computed).
// Counting-sort edges by dst; k_edge: 64 edges/block @ 4 blocks/CU (R9 structure — proven
// local optimum; R7/R10/R11 structural variants all regressed per counters).
// R12: aux launch fusion (wprep into hist grid, acm into bucket grid); k_edge gather reads
// sPair directly (first barrier removed). Scan reverted to R9 f32 single-atomic form.

#define N_NODES 50000
#define N_EDGES 800000
#define EPB 64
#define NBLK 12500             // 800000/64 exactly

typedef __attribute__((ext_vector_type(4))) float f32x4;
typedef __attribute__((ext_vector_type(8))) _Float16 f16x8;
typedef __attribute__((ext_vector_type(4))) unsigned int u32x4;
typedef __attribute__((ext_vector_type(2))) unsigned int u32x2;

__device__ __forceinline__ unsigned int pkrtz(float a, float b){   // f32x2 -> packed fp16
  auto p = __builtin_amdgcn_cvt_pkrtz(a, b);
  return __builtin_bit_cast(unsigned int, p);
}
__device__ __forceinline__ unsigned int f16bits(float f){
  _Float16 h = (_Float16)f;
  return (unsigned int)__builtin_bit_cast(unsigned short, h);
}
// packed fp16: relu(a + b), 2 channels per instruction
__device__ __forceinline__ unsigned int pkadd_relu(unsigned int a, unsigned int b){
  unsigned int s, r;
  asm("v_pk_add_f16 %0, %1, %2" : "=v"(s) : "v"(a), "v"(b));
  asm("v_pk_max_f16 %0, %1, %2" : "=v"(r) : "v"(s), "v"(0u));
  return r;
}
// monotone float->uint map: f1<f2 <=> map(f1)<map(f2); finite values map nonzero
__device__ __forceinline__ unsigned int fmap(float f){
  unsigned int u = __builtin_bit_cast(unsigned int, f);
  return (u & 0x80000000u) ? ~u : (u | 0x80000000u);
}
// int64 vs int32 edge_index: odd u32 slots of first 8 entries all zero <=> int64
__device__ __forceinline__ bool is64(const unsigned int* e){
  return (e[1] | e[3] | e[5] | e[7] | e[9] | e[11] | e[13] | e[15]) == 0u;
}

// ---- FUSED: histogram (blocks 0..3124) + weight prep (blocks 3125..3220) ----
extern "C" __global__ void k_histw(const void* __restrict__ eidx, unsigned int* __restrict__ cnt,
                                   const float* __restrict__ W1, const float* __restrict__ W2,
                                   const float* __restrict__ W3,
                                   unsigned short* __restrict__ w2s, unsigned short* __restrict__ w3s,
                                   unsigned short* __restrict__ wdf){
  const int b = blockIdx.x;
  if (b < 3125){                                       // histogram
    int i = b * 256 + threadIdx.x;
    int d = is64((const unsigned int*)eidx)
          ? (int)((const long long*)eidx)[N_EDGES + i]
          : ((const int*)eidx)[N_EDGES + i];
    atomicAdd(&cnt[d], 1u);
    return;
  }
  // weight prep: A-frag order — lane l of block (mfG*KS+ks) holds
  // A[m=16*mfG+(l&15)][k=32*ks+8*(l>>4)+j], j=0..7
  int t = (b - 3125) * 256 + threadIdx.x;              // 0..24575
  if (t < 16384){                                      // W2 / W3: K=256, 8 ks-blocks
    const float* W = (t & 8192) ? W3 : W2;
    unsigned short* o = (t & 8192) ? w3s : w2s;
    int r = t & 8191, lane = r & 63, blk = r >> 6;
    int m  = (blk >> 3) * 16 + (lane & 15);
    int k0 = (blk & 7) * 32 + (lane >> 4) * 8;
    u32x4 ov;
    #pragma unroll
    for (int j = 0; j < 4; j++){
      unsigned int lo = f16bits(W[(size_t)(k0 + 2*j    ) * 256 + m]);   // A[m][k] = W[k][m]
      unsigned int hi = f16bits(W[(size_t)(k0 + 2*j + 1) * 256 + m]);
      ov[j] = lo | (hi << 16);
    }
    *(u32x4*)(o + (size_t)r * 8) = ov;
  } else {                                             // Wd: 512 rows, K=128, 4 ks-blocks
    int r = t - 16384, lane = r & 63, blk = r >> 6;    // blk 0..127
    int m  = (blk >> 2) * 16 + (lane & 15);            // 0..511
    int k0 = (blk & 3) * 32 + (lane >> 4) * 8;         // 0..127
    u32x4 ov;
    #pragma unroll
    for (int j = 0; j < 4; j++){
      float vlo, vhi;
      int ka = k0 + 2*j, kb = k0 + 2*j + 1;
      if (m < 256){
        vlo = W1[(size_t)ka * 256 + m] - W1[(size_t)(ka + 128) * 256 + m];
        vhi = W1[(size_t)kb * 256 + m] - W1[(size_t)(kb + 128) * 256 + m];
      } else {
        vlo = W1[(size_t)(ka + 128) * 256 + (m - 256)];
        vhi = W1[(size_t)(kb + 128) * 256 + (m - 256)];
      }
      ov[j] = f16bits(vlo) | (f16bits(vhi) << 16);
    }
    *(u32x4*)(wdf + (size_t)r * 8) = ov;
  }
}

// ---- parallel exclusive scan over 50000 counters ----
extern "C" __global__ void k_psum(const unsigned int* __restrict__ cnt, unsigned int* __restrict__ bsum){
  __shared__ unsigned int red[4];
  const int b = blockIdx.x, t = threadIdx.x, i = b * 256 + t;
  unsigned int v = (i < N_NODES) ? cnt[i] : 0u;
  #pragma unroll
  for (int d = 32; d; d >>= 1) v += __shfl_down(v, d, 64);
  if ((t & 63) == 0) red[t >> 6] = v;
  __syncthreads();
  if (t == 0) bsum[b] = red[0] + red[1] + red[2] + red[3];
}
extern "C" __global__ void __launch_bounds__(256) k_bscan(const unsigned int* __restrict__ bsum,
                                                          unsigned int* __restrict__ bbase){
  __shared__ unsigned int s[256];
  const int t = threadIdx.x;
  unsigned int v = (t < 196) ? bsum[t] : 0u;
  s[t] = v; __syncthreads();
  for (int d = 1; d < 256; d <<= 1){
    unsigned int u = (t >= d) ? s[t - d] : 0u;
    __syncthreads(); s[t] += u; __syncthreads();
  }
  if (t < 196) bbase[t] = s[t] - v;               // exclusive
}
extern "C" __global__ void k_apply(const unsigned int* __restrict__ cnt,
                                   const unsigned int* __restrict__ bbase,
                                   unsigned int* __restrict__ off){
  __shared__ unsigned int s[256];
  const int b = blockIdx.x, t = threadIdx.x, i = b * 256 + t;
  unsigned int v = (i < N_NODES) ? cnt[i] : 0u;
  s[t] = v; __syncthreads();
  for (int d = 1; d < 256; d <<= 1){
    unsigned int u = (t >= d) ? s[t - d] : 0u;
    __syncthreads(); s[t] += u; __syncthreads();
  }
  if (i < N_NODES) off[i] = bbase[b] + s[t] - v;  // exclusive prefix
}

// ---- FUSED: bucket scatter (blocks 0..3124) + per-node ac precompute (3125..3906) ----
extern "C" __global__ void __launch_bounds__(256) k_bucketac(
    const void* __restrict__ eidx, unsigned int* __restrict__ cur,
    unsigned int* __restrict__ sPair,
    const float* __restrict__ x, const unsigned short* __restrict__ wdf,
    const float* __restrict__ b1, unsigned short* __restrict__ acb){
  __shared__ unsigned char smx[16384];                 // used only by acm branch
  const int b = blockIdx.x;
  if (b < 3125){                                       // bucket scatter
    int i = b * 256 + threadIdx.x;
    int s, d;
    if (is64((const unsigned int*)eidx)){
      const long long* p = (const long long*)eidx;
      s = (int)p[i]; d = (int)p[N_EDGES + i];
    } else {
      const int* p = (const int*)eidx;
      s = p[i]; d = p[N_EDGES + i];
    }
    unsigned int pos = atomicAdd(&cur[d], 1u);
    sPair[pos] = (unsigned int)s | ((unsigned int)d << 16);  // both < 50000 < 2^16
    return;
  }
  // ac precompute via MFMA: ac[n] = [a|c] fp16, a=x@(W1a-W1b)+b1, c=x@W1b
  const int tid = threadIdx.x, lane = tid & 63, w = tid >> 6;
  const int n0 = (b - 3125) * 64;
  {
    const int nl = tid >> 2, q = tid & 3;
    int node = n0 + nl; if (node > N_NODES - 1) node = N_NODES - 1;
    const f32x4* xp = (const f32x4*)(x + (size_t)node * 128 + q * 32);
    unsigned char* base = smx + (((nl >> 4) * 256 + q * 64 + (nl & 15)) << 4);
    #pragma unroll
    for (int s = 0; s < 4; s++){
      f32x4 v0 = xp[s * 2], v1 = xp[s * 2 + 1];
      u32x4 ov = { pkrtz(v0[0], v0[1]), pkrtz(v0[2], v0[3]),
                   pkrtz(v1[0], v1[1]), pkrtz(v1[2], v1[3]) };
      *(u32x4*)(base + s * 256) = ov;
    }
  }
  __syncthreads();
  const int lm = lane & 15, g = lane >> 4;
  f32x4 acc[8][4];
  #pragma unroll
  for (int mf = 0; mf < 8; mf++)
    #pragma unroll
    for (int nf = 0; nf < 4; nf++) acc[mf][nf] = (f32x4){0.f, 0.f, 0.f, 0.f};
  #pragma unroll
  for (int ks = 0; ks < 4; ks++){
    f16x8 af[8], bfr[4];
    #pragma unroll
    for (int mf = 0; mf < 8; mf++)
      af[mf] = __builtin_bit_cast(f16x8, *(const u32x4*)(wdf + (size_t)(((w * 8 + mf) * 4 + ks) * 64 + lane) * 8));
    #pragma unroll
    for (int nf = 0; nf < 4; nf++)
      bfr[nf] = __builtin_bit_cast(f16x8, *(const u32x4*)(smx + nf * 4096 + ks * 1024 + lane * 16));
    #pragma unroll
    for (int mf = 0; mf < 8; mf++)
      #pragma unroll
      for (int nf = 0; nf < 4; nf++)
        acc[mf][nf] = __builtin_amdgcn_mfma_f32_16x16x32_f16(af[mf], bfr[nf], acc[mf][nf], 0, 0, 0);
  }
  #pragma unroll
  for (int mf = 0; mf < 8; mf++){
    const int m0 = w * 128 + mf * 16 + g * 4;          // w<2 -> a half (bias), w>=2 -> c half
    f32x4 bb = (f32x4){0.f, 0.f, 0.f, 0.f};
    if (w < 2) bb = *(const f32x4*)(b1 + m0);
    #pragma unroll
    for (int nf = 0; nf < 4; nf++){
      int node = n0 + nf * 16 + lm;
      if (node < N_NODES){
        u32x2 pv = { pkrtz(acc[mf][nf][0] + bb[0], acc[mf][nf][1] + bb[1]),
                     pkrtz(acc[mf][nf][2] + bb[2], acc[mf][nf][3] + bb[3]) };
        *(u32x2*)(acb + (size_t)node * 512 + m0) = pv;
      }
    }
  }
}

// ---- fused edge MLP on dst-sorted edges: 64 edges/block, 4 waves, 4 blocks/CU ----
// h1/h2 fragment-linear LDS: ch c of edge e at 16B-slot (e>>4)*512 + (c>>5)*64 + ((c>>3)&3)*16 + (e&15).
// B-frag read = sm + nf*8192 + ks*1024 + lane*16 -> conflict-free ds_read_b128.
// Bias via MFMA C-in init. Gather reads sPair directly (no leading barrier).
// h3 staged f32 in two 32-row halves + per-dst-group running max, one atomic burst per group.
extern "C" __global__ void __launch_bounds__(256, 4) k_edge(
    const unsigned short* __restrict__ acb,
    const unsigned short* __restrict__ w2f, const unsigned short* __restrict__ w3f,
    const float* __restrict__ b2, const float* __restrict__ b3,
    const unsigned int* __restrict__ sPair,
    unsigned int* __restrict__ outu){
  __shared__ unsigned char sm[32768];                  // 64 edges x 256 ch fp16
  __shared__ int dstI[EPB];
  const int tid = threadIdx.x;
  const int lane = tid & 63;
  const int w = tid >> 6;

  // bijective XCD chunk swizzle: 12500 = 8*1562 + 4
  const int bid = blockIdx.x;
  const int xcd = bid & 7, idx = bid >> 3;
  const int sb = (xcd < 4) ? xcd * 1563 : 4 * 1563 + (xcd - 4) * 1562;
  const int e0 = (sb + idx) * EPB;

  // prefetch W2 ks=0 A-frags
  f16x8 afp[4];
  #pragma unroll
  for (int mf = 0; mf < 4; mf++)
    afp[mf] = __builtin_bit_cast(f16x8, *(const u32x4*)(w2f + (size_t)(((w * 4 + mf) * 8 + 0) * 64 + lane) * 8));

  if (tid < EPB) dstI[tid] = (int)(sPair[e0 + tid] >> 16);   // for the scan phase

  { // gather: h1 = relu(a[dst]+c[src]) packed fp16. 4 threads/edge, 64 ch each.
    // Direct sPair read (L1-hot, 4x redundant) — no barrier needed before gather.
    const int e = tid >> 2, q = tid & 3;
    const unsigned int pr = sPair[e0 + e];
    const unsigned short* pa = acb + (size_t)(pr >> 16) * 512 + q * 64;            // a[dst]
    const unsigned short* pc = acb + (size_t)(pr & 0xFFFFu) * 512 + 256 + q * 64;  // c[src]
    unsigned char* base = sm + (e >> 4) * 8192 + (e & 15) * 16;
    #pragma unroll
    for (int j = 0; j < 8; j++){                        // chunk j: channels q*64+j*8 ..+7
      u32x4 ua = *(const u32x4*)(pa + j * 8);
      u32x4 uc = *(const u32x4*)(pc + j * 8);
      u32x4 ov;
      #pragma unroll
      for (int t2 = 0; t2 < 4; t2++) ov[t2] = pkadd_relu(ua[t2], uc[t2]);
      *(u32x4*)(base + (q * 2 + (j >> 2)) * 1024 + (j & 3) * 256) = ov;
    }
  }
  __syncthreads();

  const int lm = lane & 15, g = lane >> 4;
  f32x4 acc[4][4];
  { // init acc with b2 (C-in bias): lane rows = channels m0..m0+3, same for all edges
    #pragma unroll
    for (int mf = 0; mf < 4; mf++){
      const f32x4 bb = *(const f32x4*)(b2 + w * 64 + mf * 16 + g * 4);
      #pragma unroll
      for (int nf = 0; nf < 4; nf++) acc[mf][nf] = bb;
    }
  }

  // G1: h2^T = W2^T @ h1^T + b2
  #pragma unroll
  for (int ks = 0; ks < 8; ks++){
    f16x8 af[4], bfr[4];
    #pragma unroll
    for (int mf = 0; mf < 4; mf++)
      af[mf] = (ks == 0) ? afp[mf]
             : __builtin_bit_cast(f16x8, *(const u32x4*)(w2f + (size_t)(((w * 4 + mf) * 8 + ks) * 64 + lane) * 8));
    #pragma unroll
    for (int nf = 0; nf < 4; nf++)
      bfr[nf] = __builtin_bit_cast(f16x8, *(const u32x4*)(sm + nf * 8192 + ks * 1024 + lane * 16));
    __builtin_amdgcn_s_setprio(1);
    #pragma unroll
    for (int mf = 0; mf < 4; mf++)
      #pragma unroll
      for (int nf = 0; nf < 4; nf++)
        acc[mf][nf] = __builtin_amdgcn_mfma_f32_16x16x32_f16(af[mf], bfr[nf], acc[mf][nf], 0, 0, 0);
    __builtin_amdgcn_s_setprio(0);
  }

  // prefetch W3 ks=0 before the barrier
  #pragma unroll
  for (int mf = 0; mf < 4; mf++)
    afp[mf] = __builtin_bit_cast(f16x8, *(const u32x4*)(w3f + (size_t)(((w * 4 + mf) * 8 + 0) * 64 + lane) * 8));
  __syncthreads();   // all waves done reading h1

  { // relu -> h2 fp16, fragment-linear, in place (bias already in acc)
    #pragma unroll
    for (int mf = 0; mf < 4; mf++){
      const int m0 = w * 64 + mf * 16 + g * 4;
      const int boff = (m0 >> 5) * 1024 + ((m0 >> 3) & 3) * 256 + lm * 16 + (m0 & 7) * 2;
      #pragma unroll
      for (int nf = 0; nf < 4; nf++){
        float v0 = fmaxf(acc[mf][nf][0], 0.f);
        float v1 = fmaxf(acc[mf][nf][1], 0.f);
        float v2 = fmaxf(acc[mf][nf][2], 0.f);
        float v3 = fmaxf(acc[mf][nf][3], 0.f);
        u32x2 pv = { pkrtz(v0, v1), pkrtz(v2, v3) };
        *(u32x2*)(sm + nf * 8192 + boff) = pv;
      }
    }
  }
  __syncthreads();

  { // init acc with b3 for G2
    #pragma unroll
    for (int mf = 0; mf < 4; mf++){
      const f32x4 bb = *(const f32x4*)(b3 + w * 64 + mf * 16 + g * 4);
      #pragma unroll
      for (int nf = 0; nf < 4; nf++) acc[mf][nf] = bb;
    }
  }
  // G2: h3^T = W3^T @ h2^T + b3
  #pragma unroll
  for (int ks = 0; ks < 8; ks++){
    f16x8 af[4], bfr[4];
    #pragma unroll
    for (int mf = 0; mf < 4; mf++)
      af[mf] = (ks == 0) ? afp[mf]
             : __builtin_bit_cast(f16x8, *(const u32x4*)(w3f + (size_t)(((w * 4 + mf) * 8 + ks) * 64 + lane) * 8));
    #pragma unroll
    for (int nf = 0; nf < 4; nf++)
      bfr[nf] = __builtin_bit_cast(f16x8, *(const u32x4*)(sm + nf * 8192 + ks * 1024 + lane * 16));
    __builtin_amdgcn_s_setprio(1);
    #pragma unroll
    for (int mf = 0; mf < 4; mf++)
      #pragma unroll
      for (int nf = 0; nf < 4; nf++)
        acc[mf][nf] = __builtin_amdgcn_mfma_f32_16x16x32_f16(af[mf], bfr[nf], acc[mf][nf], 0, 0, 0);
    __builtin_amdgcn_s_setprio(0);
  }
  __syncthreads();   // all h2 reads done before h3 staging overwrites the buffer

  // h3 staging (f32, 32 rows per half, XOR) + per-dst-group float running max.
  float vmaxf = -__builtin_inff();
  int curDst = dstI[0];
  const int t4 = tid * 4;
  #pragma unroll
  for (int half = 0; half < 2; half++){
    #pragma unroll
    for (int mf = 0; mf < 4; mf++){
      const int m0 = w * 64 + mf * 16 + g * 4;
      #pragma unroll
      for (int nfl = 0; nfl < 2; nfl++){
        const int r = nfl * 16 + lm;                    // row within half
        const int nf = half * 2 + nfl;
        *(f32x4*)(sm + r * 1024 + ((m0 * 4) ^ ((r & 7) << 4))) = acc[mf][nf];
      }
    }
    __syncthreads();
    for (int it = 0; it < 32; it++){
      float v = *(const float*)(sm + it * 1024 + (t4 ^ ((it & 7) << 4)));
      const int d = dstI[half * 32 + it];               // uniform across block
      if (d != curDst){                                 // flush previous group (coalesced 1KB)
        atomicMax(outu + (size_t)curDst * 256 + tid, fmap(vmaxf));
        curDst = d; vmaxf = -__builtin_inff();
      }
      vmaxf = fmaxf(vmaxf, v);
    }
    __syncthreads();                                    // scan reads done before next staging
  }
  atomicMax(outu + (size_t)curDst * 256 + tid, fmap(vmaxf));   // final flush
}

// ---- unmap uint->float; untouched (0) cells = empty segments -> 0.0 ----
extern "C" __global__ void k_fix(u32x4* __restrict__ o){
  size_t i = (size_t)blockIdx.x * 256 + threadIdx.x;
  u32x4 u = o[i];
  #pragma unroll
  for (int j = 0; j < 4; j++)
    u[j] = (u[j] == 0u) ? 0u : ((u[j] & 0x80000000u) ? (u[j] ^ 0x80000000u) : ~u[j]);
  o[i] = u;
}

extern "C" void kernel_launch(void* const* d_in, const int* in_sizes, int n_in,
                              void* d_out, int out_size, void* d_ws, size_t ws_size,
                              hipStream_t stream){
  const float* x  = (const float*)d_in[0];
  const void*  ei = d_in[1];
  const float* W1 = (const float*)d_in[2];
  const float* b1 = (const float*)d_in[3];
  const float* W2 = (const float*)d_in[4];
  const float* b2 = (const float*)d_in[5];
  const float* W3 = (const float*)d_in[6];
  const float* b3 = (const float*)d_in[7];

  const size_t AC_BYTES = (size_t)N_NODES * 512 * 2;  // 51.2 MB combined [a|c] fp16
  const size_t W_BYTES  = 256 * 256 * 2;              // 128 KB each: w2s, w3s, wdf
  const size_t P_BYTES  = (size_t)N_EDGES * 4;        // 3.2 MB sorted pairs
  const size_t C_BYTES  = 200704;                     // 50000 u32, padded
  char* ws = (char*)d_ws;
  size_t o = 0;
  unsigned short* acb  = (unsigned short*)(ws + o); o += AC_BYTES;
  unsigned short* w2s  = (unsigned short*)(ws + o); o += W_BYTES;
  unsigned short* w3s  = (unsigned short*)(ws + o); o += W_BYTES;
  unsigned short* wdf  = (unsigned short*)(ws + o); o += W_BYTES;
  unsigned int*  sPair = (unsigned int*)(ws + o);   o += P_BYTES;
  unsigned int*  cnt   = (unsigned int*)(ws + o);   o += C_BYTES;
  unsigned int*  offA  = (unsigned int*)(ws + o);   o += C_BYTES;
  unsigned int*  bsum  = (unsigned int*)(ws + o);   o += 1024;
  unsigned int*  bbase = (unsigned int*)(ws + o);   o += 1024;
  if (ws_size < o) return;   // insufficient scratch

  (void)hipMemsetAsync(cnt, 0, C_BYTES, stream);
  k_histw<<<3125 + 96, 256, 0, stream>>>(ei, cnt, W1, W2, W3, w2s, w3s, wdf);
  k_psum<<<196, 256, 0, stream>>>(cnt, bsum);
  k_bscan<<<1, 256, 0, stream>>>(bsum, bbase);
  k_apply<<<196, 256, 0, stream>>>(cnt, bbase, offA);
  k_bucketac<<<3125 + 782, 256, 0, stream>>>(ei, offA, sPair, x, wdf, b1, acb);
  (void)hipMemsetAsync(d_out, 0, (size_t)out_size * 4, stream);
  k_edge<<<NBLK, 256, 0, stream>>>(acb, w2s, w3s, b2, b3, sPair, (unsigned int*)d_out);
  k_fix<<<out_size / 1024, 256, 0, stream>>>((u32x4*)d_out);
}

// Round 13
// 418.912 us; speedup vs baseline: 1.1347x; 1.0320x over previous
//
#include <hip/hip_runtime.h>
#include <stdint.h>

// EdgeConv fused: out[i] = max over edges (j->i) of MLP3(concat[x_i, x_j-x_i])
// Layer-1 split: e@W1 = x_i@(W1a-W1b) + x_j@W1b. Per-node ac[n] = [a|c] (fp16, MFMA-computed).
// Counting-sort edges by dst; k_edge: 64 edges/block @ 4 blocks/CU (R9 structure).
// R13: h3 staged packed-fp16 in ONE 32KB round + CONTIGUOUS-halves pk16 scan (R11's
// regression was interleaved rows: every group flushed twice -> WRITE 280MB; contiguous
// halves flush each group once). Aux: k_bscan folded into k_apply (redundant 196-scan),
// memset(d_out) folded into k_apply as grid-stride stores. 7 dispatches (was 9).

#define N_NODES 50000
#define N_EDGES 800000
#define EPB 64
#define NBLK 12500             // 800000/64 exactly

typedef __attribute__((ext_vector_type(4))) float f32x4;
typedef __attribute__((ext_vector_type(8))) _Float16 f16x8;
typedef __attribute__((ext_vector_type(4))) unsigned int u32x4;
typedef __attribute__((ext_vector_type(2))) unsigned int u32x2;

__device__ __forceinline__ unsigned int pkrtz(float a, float b){   // f32x2 -> packed fp16
  auto p = __builtin_amdgcn_cvt_pkrtz(a, b);
  return __builtin_bit_cast(unsigned int, p);
}
__device__ __forceinline__ unsigned int f16bits(float f){
  _Float16 h = (_Float16)f;
  return (unsigned int)__builtin_bit_cast(unsigned short, h);
}
// packed fp16: relu(a + b), 2 channels per instruction
__device__ __forceinline__ unsigned int pkadd_relu(unsigned int a, unsigned int b){
  unsigned int s, r;
  asm("v_pk_add_f16 %0, %1, %2" : "=v"(s) : "v"(a), "v"(b));
  asm("v_pk_max_f16 %0, %1, %2" : "=v"(r) : "v"(s), "v"(0u));
  return r;
}
__device__ __forceinline__ unsigned int pkmax(unsigned int a, unsigned int b){
  unsigned int r;
  asm("v_pk_max_f16 %0, %1, %2" : "=v"(r) : "v"(a), "v"(b));
  return r;
}
__device__ __forceinline__ float f16lo2f(unsigned int v){
  return (float)__builtin_bit_cast(_Float16, (unsigned short)(v & 0xFFFFu));
}
__device__ __forceinline__ float f16hi2f(unsigned int v){
  return (float)__builtin_bit_cast(_Float16, (unsigned short)(v >> 16));
}
// monotone float->uint map: f1<f2 <=> map(f1)<map(f2); finite values map nonzero
__device__ __forceinline__ unsigned int fmap(float f){
  unsigned int u = __builtin_bit_cast(unsigned int, f);
  return (u & 0x80000000u) ? ~u : (u | 0x80000000u);
}
// int64 vs int32 edge_index: odd u32 slots of first 8 entries all zero <=> int64
__device__ __forceinline__ bool is64(const unsigned int* e){
  return (e[1] | e[3] | e[5] | e[7] | e[9] | e[11] | e[13] | e[15]) == 0u;
}

// ---- FUSED: histogram (blocks 0..3124) + weight prep (blocks 3125..3220) ----
extern "C" __global__ void k_histw(const void* __restrict__ eidx, unsigned int* __restrict__ cnt,
                                   const float* __restrict__ W1, const float* __restrict__ W2,
                                   const float* __restrict__ W3,
                                   unsigned short* __restrict__ w2s, unsigned short* __restrict__ w3s,
                                   unsigned short* __restrict__ wdf){
  const int b = blockIdx.x;
  if (b < 3125){                                       // histogram
    int i = b * 256 + threadIdx.x;
    int d = is64((const unsigned int*)eidx)
          ? (int)((const long long*)eidx)[N_EDGES + i]
          : ((const int*)eidx)[N_EDGES + i];
    atomicAdd(&cnt[d], 1u);
    return;
  }
  // weight prep: A-frag order — lane l of block (mfG*KS+ks) holds
  // A[m=16*mfG+(l&15)][k=32*ks+8*(l>>4)+j], j=0..7
  int t = (b - 3125) * 256 + threadIdx.x;              // 0..24575
  if (t < 16384){                                      // W2 / W3: K=256, 8 ks-blocks
    const float* W = (t & 8192) ? W3 : W2;
    unsigned short* o = (t & 8192) ? w3s : w2s;
    int r = t & 8191, lane = r & 63, blk = r >> 6;
    int m  = (blk >> 3) * 16 + (lane & 15);
    int k0 = (blk & 7) * 32 + (lane >> 4) * 8;
    u32x4 ov;
    #pragma unroll
    for (int j = 0; j < 4; j++){
      unsigned int lo = f16bits(W[(size_t)(k0 + 2*j    ) * 256 + m]);   // A[m][k] = W[k][m]
      unsigned int hi = f16bits(W[(size_t)(k0 + 2*j + 1) * 256 + m]);
      ov[j] = lo | (hi << 16);
    }
    *(u32x4*)(o + (size_t)r * 8) = ov;
  } else {                                             // Wd: 512 rows, K=128, 4 ks-blocks
    int r = t - 16384, lane = r & 63, blk = r >> 6;    // blk 0..127
    int m  = (blk >> 2) * 16 + (lane & 15);            // 0..511
    int k0 = (blk & 3) * 32 + (lane >> 4) * 8;         // 0..127
    u32x4 ov;
    #pragma unroll
    for (int j = 0; j < 4; j++){
      float vlo, vhi;
      int ka = k0 + 2*j, kb = k0 + 2*j + 1;
      if (m < 256){
        vlo = W1[(size_t)ka * 256 + m] - W1[(size_t)(ka + 128) * 256 + m];
        vhi = W1[(size_t)kb * 256 + m] - W1[(size_t)(kb + 128) * 256 + m];
      } else {
        vlo = W1[(size_t)(ka + 128) * 256 + (m - 256)];
        vhi = W1[(size_t)(kb + 128) * 256 + (m - 256)];
      }
      ov[j] = f16bits(vlo) | (f16bits(vhi) << 16);
    }
    *(u32x4*)(wdf + (size_t)r * 8) = ov;
  }
}

// ---- per-block partial sums over 50000 counters ----
extern "C" __global__ void k_psum(const unsigned int* __restrict__ cnt, unsigned int* __restrict__ bsum){
  __shared__ unsigned int red[4];
  const int b = blockIdx.x, t = threadIdx.x, i = b * 256 + t;
  unsigned int v = (i < N_NODES) ? cnt[i] : 0u;
  #pragma unroll
  for (int d = 32; d; d >>= 1) v += __shfl_down(v, d, 64);
  if ((t & 63) == 0) red[t >> 6] = v;
  __syncthreads();
  if (t == 0) bsum[b] = red[0] + red[1] + red[2] + red[3];
}

// ---- apply: each block re-scans bsum[196] itself (no k_bscan), computes exclusive
// offsets for its 256 counters, and zeroes a grid-stride chunk of d_out. ----
extern "C" __global__ void __launch_bounds__(256) k_apply(
    const unsigned int* __restrict__ cnt, const unsigned int* __restrict__ bsum,
    unsigned int* __restrict__ off, u32x4* __restrict__ outz, int nquads){
  __shared__ unsigned int ps[256];
  __shared__ unsigned int s[256];
  const int b = blockIdx.x, t = threadIdx.x, i = b * 256 + t;
  // zero d_out chunk (replaces the 51MB memsetAsync dispatch)
  const u32x4 z = (u32x4){0u, 0u, 0u, 0u};
  for (int q = i; q < nquads; q += 196 * 256) outz[q] = z;
  // redundant scan of the 196 block sums -> this block's base
  unsigned int bv = (t < 196) ? bsum[t] : 0u;
  ps[t] = bv; __syncthreads();
  for (int d = 1; d < 256; d <<= 1){
    unsigned int u = (t >= d) ? ps[t - d] : 0u;
    __syncthreads(); ps[t] += u; __syncthreads();
  }
  const unsigned int base = (b > 0) ? ps[b - 1] : 0u;
  // scan own 256 counters
  unsigned int v = (i < N_NODES) ? cnt[i] : 0u;
  s[t] = v; __syncthreads();
  for (int d = 1; d < 256; d <<= 1){
    unsigned int u = (t >= d) ? s[t - d] : 0u;
    __syncthreads(); s[t] += u; __syncthreads();
  }
  if (i < N_NODES) off[i] = base + s[t] - v;      // exclusive prefix
}

// ---- FUSED: bucket scatter (blocks 0..3124) + per-node ac precompute (3125..3906) ----
extern "C" __global__ void __launch_bounds__(256) k_bucketac(
    const void* __restrict__ eidx, unsigned int* __restrict__ cur,
    unsigned int* __restrict__ sPair,
    const float* __restrict__ x, const unsigned short* __restrict__ wdf,
    const float* __restrict__ b1, unsigned short* __restrict__ acb){
  __shared__ unsigned char smx[16384];                 // used only by acm branch
  const int b = blockIdx.x;
  if (b < 3125){                                       // bucket scatter
    int i = b * 256 + threadIdx.x;
    int s, d;
    if (is64((const unsigned int*)eidx)){
      const long long* p = (const long long*)eidx;
      s = (int)p[i]; d = (int)p[N_EDGES + i];
    } else {
      const int* p = (const int*)eidx;
      s = p[i]; d = p[N_EDGES + i];
    }
    unsigned int pos = atomicAdd(&cur[d], 1u);
    sPair[pos] = (unsigned int)s | ((unsigned int)d << 16);  // both < 50000 < 2^16
    return;
  }
  // ac precompute via MFMA: ac[n] = [a|c] fp16, a=x@(W1a-W1b)+b1, c=x@W1b
  const int tid = threadIdx.x, lane = tid & 63, w = tid >> 6;
  const int n0 = (b - 3125) * 64;
  {
    const int nl = tid >> 2, q = tid & 3;
    int node = n0 + nl; if (node > N_NODES - 1) node = N_NODES - 1;
    const f32x4* xp = (const f32x4*)(x + (size_t)node * 128 + q * 32);
    unsigned char* base = smx + (((nl >> 4) * 256 + q * 64 + (nl & 15)) << 4);
    #pragma unroll
    for (int s = 0; s < 4; s++){
      f32x4 v0 = xp[s * 2], v1 = xp[s * 2 + 1];
      u32x4 ov = { pkrtz(v0[0], v0[1]), pkrtz(v0[2], v0[3]),
                   pkrtz(v1[0], v1[1]), pkrtz(v1[2], v1[3]) };
      *(u32x4*)(base + s * 256) = ov;
    }
  }
  __syncthreads();
  const int lm = lane & 15, g = lane >> 4;
  f32x4 acc[8][4];
  #pragma unroll
  for (int mf = 0; mf < 8; mf++)
    #pragma unroll
    for (int nf = 0; nf < 4; nf++) acc[mf][nf] = (f32x4){0.f, 0.f, 0.f, 0.f};
  #pragma unroll
  for (int ks = 0; ks < 4; ks++){
    f16x8 af[8], bfr[4];
    #pragma unroll
    for (int mf = 0; mf < 8; mf++)
      af[mf] = __builtin_bit_cast(f16x8, *(const u32x4*)(wdf + (size_t)(((w * 8 + mf) * 4 + ks) * 64 + lane) * 8));
    #pragma unroll
    for (int nf = 0; nf < 4; nf++)
      bfr[nf] = __builtin_bit_cast(f16x8, *(const u32x4*)(smx + nf * 4096 + ks * 1024 + lane * 16));
    #pragma unroll
    for (int mf = 0; mf < 8; mf++)
      #pragma unroll
      for (int nf = 0; nf < 4; nf++)
        acc[mf][nf] = __builtin_amdgcn_mfma_f32_16x16x32_f16(af[mf], bfr[nf], acc[mf][nf], 0, 0, 0);
  }
  #pragma unroll
  for (int mf = 0; mf < 8; mf++){
    const int m0 = w * 128 + mf * 16 + g * 4;          // w<2 -> a half (bias), w>=2 -> c half
    f32x4 bb = (f32x4){0.f, 0.f, 0.f, 0.f};
    if (w < 2) bb = *(const f32x4*)(b1 + m0);
    #pragma unroll
    for (int nf = 0; nf < 4; nf++){
      int node = n0 + nf * 16 + lm;
      if (node < N_NODES){
        u32x2 pv = { pkrtz(acc[mf][nf][0] + bb[0], acc[mf][nf][1] + bb[1]),
                     pkrtz(acc[mf][nf][2] + bb[2], acc[mf][nf][3] + bb[3]) };
        *(u32x2*)(acb + (size_t)node * 512 + m0) = pv;
      }
    }
  }
}

// ---- fused edge MLP on dst-sorted edges: 64 edges/block, 4 waves, 4 blocks/CU ----
// h1/h2 fragment-linear LDS: ch c of edge e at 16B-slot (e>>4)*512 + (c>>5)*64 + ((c>>3)&3)*16 + (e&15).
// B-frag read = sm + nf*8192 + ks*1024 + lane*16 -> conflict-free ds_read_b128.
// Bias via MFMA C-in init. Gather reads sPair directly (no leading barrier).
// h3: ONE 32KB packed-fp16 staging round; contiguous-halves pk16 scan (sub0 rows 0..31,
// sub1 rows 32..63) -> each group flushed once; atomicMax merges the <=1 boundary group.
extern "C" __global__ void __launch_bounds__(256, 4) k_edge(
    const unsigned short* __restrict__ acb,
    const unsigned short* __restrict__ w2f, const unsigned short* __restrict__ w3f,
    const float* __restrict__ b2, const float* __restrict__ b3,
    const unsigned int* __restrict__ sPair,
    unsigned int* __restrict__ outu){
  __shared__ unsigned char sm[32768];                  // 64 edges x 256 ch fp16
  __shared__ int dstI[EPB];
  const int tid = threadIdx.x;
  const int lane = tid & 63;
  const int w = tid >> 6;

  // bijective XCD chunk swizzle: 12500 = 8*1562 + 4
  const int bid = blockIdx.x;
  const int xcd = bid & 7, idx = bid >> 3;
  const int sb = (xcd < 4) ? xcd * 1563 : 4 * 1563 + (xcd - 4) * 1562;
  const int e0 = (sb + idx) * EPB;

  // prefetch W2 ks=0 A-frags
  f16x8 afp[4];
  #pragma unroll
  for (int mf = 0; mf < 4; mf++)
    afp[mf] = __builtin_bit_cast(f16x8, *(const u32x4*)(w2f + (size_t)(((w * 4 + mf) * 8 + 0) * 64 + lane) * 8));

  if (tid < EPB) dstI[tid] = (int)(sPair[e0 + tid] >> 16);   // for the scan phase

  { // gather: h1 = relu(a[dst]+c[src]) packed fp16. 4 threads/edge, 64 ch each.
    const int e = tid >> 2, q = tid & 3;
    const unsigned int pr = sPair[e0 + e];                   // L1-hot redundant read
    const unsigned short* pa = acb + (size_t)(pr >> 16) * 512 + q * 64;            // a[dst]
    const unsigned short* pc = acb + (size_t)(pr & 0xFFFFu) * 512 + 256 + q * 64;  // c[src]
    unsigned char* base = sm + (e >> 4) * 8192 + (e & 15) * 16;
    #pragma unroll
    for (int j = 0; j < 8; j++){                        // chunk j: channels q*64+j*8 ..+7
      u32x4 ua = *(const u32x4*)(pa + j * 8);
      u32x4 uc = *(const u32x4*)(pc + j * 8);
      u32x4 ov;
      #pragma unroll
      for (int t2 = 0; t2 < 4; t2++) ov[t2] = pkadd_relu(ua[t2], uc[t2]);
      *(u32x4*)(base + (q * 2 + (j >> 2)) * 1024 + (j & 3) * 256) = ov;
    }
  }
  __syncthreads();

  const int lm = lane & 15, g = lane >> 4;
  f32x4 acc[4][4];
  { // init acc with b2 (C-in bias)
    #pragma unroll
    for (int mf = 0; mf < 4; mf++){
      const f32x4 bb = *(const f32x4*)(b2 + w * 64 + mf * 16 + g * 4);
      #pragma unroll
      for (int nf = 0; nf < 4; nf++) acc[mf][nf] = bb;
    }
  }

  // G1: h2^T = W2^T @ h1^T + b2
  #pragma unroll
  for (int ks = 0; ks < 8; ks++){
    f16x8 af[4], bfr[4];
    #pragma unroll
    for (int mf = 0; mf < 4; mf++)
      af[mf] = (ks == 0) ? afp[mf]
             : __builtin_bit_cast(f16x8, *(const u32x4*)(w2f + (size_t)(((w * 4 + mf) * 8 + ks) * 64 + lane) * 8));
    #pragma unroll
    for (int nf = 0; nf < 4; nf++)
      bfr[nf] = __builtin_bit_cast(f16x8, *(const u32x4*)(sm + nf * 8192 + ks * 1024 + lane * 16));
    __builtin_amdgcn_s_setprio(1);
    #pragma unroll
    for (int mf = 0; mf < 4; mf++)
      #pragma unroll
      for (int nf = 0; nf < 4; nf++)
        acc[mf][nf] = __builtin_amdgcn_mfma_f32_16x16x32_f16(af[mf], bfr[nf], acc[mf][nf], 0, 0, 0);
    __builtin_amdgcn_s_setprio(0);
  }

  // prefetch W3 ks=0 before the barrier
  #pragma unroll
  for (int mf = 0; mf < 4; mf++)
    afp[mf] = __builtin_bit_cast(f16x8, *(const u32x4*)(w3f + (size_t)(((w * 4 + mf) * 8 + 0) * 64 + lane) * 8));
  __syncthreads();   // all waves done reading h1

  { // relu -> h2 fp16, fragment-linear, in place (bias already in acc)
    #pragma unroll
    for (int mf = 0; mf < 4; mf++){
      const int m0 = w * 64 + mf * 16 + g * 4;
      const int boff = (m0 >> 5) * 1024 + ((m0 >> 3) & 3) * 256 + lm * 16 + (m0 & 7) * 2;
      #pragma unroll
      for (int nf = 0; nf < 4; nf++){
        float v0 = fmaxf(acc[mf][nf][0], 0.f);
        float v1 = fmaxf(acc[mf][nf][1], 0.f);
        float v2 = fmaxf(acc[mf][nf][2], 0.f);
        float v3 = fmaxf(acc[mf][nf][3], 0.f);
        u32x2 pv = { pkrtz(v0, v1), pkrtz(v2, v3) };
        *(u32x2*)(sm + nf * 8192 + boff) = pv;
      }
    }
  }
  __syncthreads();

  { // init acc with b3 for G2
    #pragma unroll
    for (int mf = 0; mf < 4; mf++){
      const f32x4 bb = *(const f32x4*)(b3 + w * 64 + mf * 16 + g * 4);
      #pragma unroll
      for (int nf = 0; nf < 4; nf++) acc[mf][nf] = bb;
    }
  }
  // G2: h3^T = W3^T @ h2^T + b3
  #pragma unroll
  for (int ks = 0; ks < 8; ks++){
    f16x8 af[4], bfr[4];
    #pragma unroll
    for (int mf = 0; mf < 4; mf++)
      af[mf] = (ks == 0) ? afp[mf]
             : __builtin_bit_cast(f16x8, *(const u32x4*)(w3f + (size_t)(((w * 4 + mf) * 8 + ks) * 64 + lane) * 8));
    #pragma unroll
    for (int nf = 0; nf < 4; nf++)
      bfr[nf] = __builtin_bit_cast(f16x8, *(const u32x4*)(sm + nf * 8192 + ks * 1024 + lane * 16));
    __builtin_amdgcn_s_setprio(1);
    #pragma unroll
    for (int mf = 0; mf < 4; mf++)
      #pragma unroll
      for (int nf = 0; nf < 4; nf++)
        acc[mf][nf] = __builtin_amdgcn_mfma_f32_16x16x32_f16(af[mf], bfr[nf], acc[mf][nf], 0, 0, 0);
    __builtin_amdgcn_s_setprio(0);
  }
  __syncthreads();   // all h2 reads done before h3 staging overwrites the buffer

  { // h3 staging: packed fp16, 64 rows x 512B = 32KB, ONE round
    #pragma unroll
    for (int mf = 0; mf < 4; mf++){
      const int m0 = w * 64 + mf * 16 + g * 4;
      #pragma unroll
      for (int nf = 0; nf < 4; nf++){
        const int r = nf * 16 + lm;
        u32x2 pv = { pkrtz(acc[mf][nf][0], acc[mf][nf][1]),
                     pkrtz(acc[mf][nf][2], acc[mf][nf][3]) };
        *(u32x2*)(sm + r * 512 + ((m0 * 2) ^ ((r & 7) << 4))) = pv;
      }
    }
  }
  __syncthreads();

  // contiguous-halves pk16 scan: p = tid&127 -> channels 2p,2p+1; sub = tid>>7 -> rows
  // sub*32..sub*32+31 (contiguous => each dst-group flushed by exactly one sub, except
  // <=1 boundary group which both flush; atomicMax merges). Every flush contains >=1 row.
  {
    const int p = tid & 127, sub = tid >> 7;
    unsigned int vmax = 0xFC00FC00u;                    // packed (-inf, -inf)
    int curDst = dstI[sub * 32];
    for (int k2 = 0; k2 < 32; k2++){
      const int rl = sub * 32 + k2;
      unsigned int v = *(const unsigned int*)(sm + rl * 512 + ((p * 4) ^ ((rl & 7) << 4)));
      const int d = dstI[rl];
      if (d != curDst){                                 // flush previous group
        unsigned int* o = outu + (size_t)curDst * 256 + 2 * p;
        atomicMax(o,     fmap(f16lo2f(vmax)));
        atomicMax(o + 1, fmap(f16hi2f(vmax)));
        curDst = d; vmax = 0xFC00FC00u;
      }
      vmax = pkmax(vmax, v);
    }
    unsigned int* o = outu + (size_t)curDst * 256 + 2 * p;
    atomicMax(o,     fmap(f16lo2f(vmax)));              // final flush
    atomicMax(o + 1, fmap(f16hi2f(vmax)));
  }
}

// ---- unmap uint->float; untouched (0) cells = empty segments -> 0.0 ----
extern "C" __global__ void k_fix(u32x4* __restrict__ o){
  size_t i = (size_t)blockIdx.x * 256 + threadIdx.x;
  u32x4 u = o[i];
  #pragma unroll
  for (int j = 0; j < 4; j++)
    u[j] = (u[j] == 0u) ? 0u : ((u[j] & 0x80000000u) ? (u[j] ^ 0x80000000u) : ~u[j]);
  o[i] = u;
}

extern "C" void kernel_launch(void* const* d_in, const int* in_sizes, int n_in,
                              void* d_out, int out_size, void* d_ws, size_t ws_size,
                              hipStream_t stream){
  const float* x  = (const float*)d_in[0];
  const void*  ei = d_in[1];
  const float* W1 = (const float*)d_in[2];
  const float* b1 = (const float*)d_in[3];
  const float* W2 = (const float*)d_in[4];
  const float* b2 = (const float*)d_in[5];
  const float* W3 = (const float*)d_in[6];
  const float* b3 = (const float*)d_in[7];

  const size_t AC_BYTES = (size_t)N_NODES * 512 * 2;  // 51.2 MB combined [a|c] fp16
  const size_t W_BYTES  = 256 * 256 * 2;              // 128 KB each: w2s, w3s, wdf
  const size_t P_BYTES  = (size_t)N_EDGES * 4;        // 3.2 MB sorted pairs
  const size_t C_BYTES  = 200704;                     // 50000 u32, padded
  char* ws = (char*)d_ws;
  size_t o = 0;
  unsigned short* acb  = (unsigned short*)(ws + o); o += AC_BYTES;
  unsigned short* w2s  = (unsigned short*)(ws + o); o += W_BYTES;
  unsigned short* w3s  = (unsigned short*)(ws + o); o += W_BYTES;
  unsigned short* wdf  = (unsigned short*)(ws + o); o += W_BYTES;
  unsigned int*  sPair = (unsigned int*)(ws + o);   o += P_BYTES;
  unsigned int*  cnt   = (unsigned int*)(ws + o);   o += C_BYTES;
  unsigned int*  offA  = (unsigned int*)(ws + o);   o += C_BYTES;
  unsigned int*  bsum  = (unsigned int*)(ws + o);   o += 1024;
  if (ws_size < o) return;   // insufficient scratch

  (void)hipMemsetAsync(cnt, 0, C_BYTES, stream);
  k_histw<<<3125 + 96, 256, 0, stream>>>(ei, cnt, W1, W2, W3, w2s, w3s, wdf);
  k_psum<<<196, 256, 0, stream>>>(cnt, bsum);
  k_apply<<<196, 256, 0, stream>>>(cnt, bsum, offA, (u32x4*)d_out, out_size / 4);
  k_bucketac<<<3125 + 782, 256, 0, stream>>>(ei, offA, sPair, x, wdf, b1, acb);
  k_edge<<<NBLK, 256, 0, stream>>>(acb, w2s, w3s, b2, b3, sPair, (unsigned int*)d_out);
  k_fix<<<out_size / 1024, 256, 0, stream>>>((u32x4*)d_out);
}